// Round 8
// baseline (108.174 us; speedup 1.0000x reference)
//
#include <hip/hip_runtime.h>
#include <hip/hip_cooperative_groups.h>

namespace cg = cooperative_groups;

// x (16384 x 4096 fp32), W (4096 x 4096 fp32)
// out[b] = 0.75 * dot(x[b,:], colsum(W)), shape (16384,1) fp32.
// Memory-bound: 320 MB compulsory read -> ~46.5 us floor @ 6.9 TB/s (fill rate).

#define N_COLS 4096
#define BATCH  16384
#define SCALE  0.75f   // SCALING_FACTOR / 2.0

typedef float f32x4 __attribute__((ext_vector_type(4)));

__device__ __forceinline__ f32x4 ntload4(const float* p) {
    return __builtin_nontemporal_load(reinterpret_cast<const f32x4*>(p));
}

// ================= Fused cooperative kernel =================
// Phase 1: atomic-free colsum partials. 512 units = (256 col-tiles x 2 row
// halves). Block owns 16 cols x 2048 rows exclusively (R6-proven pattern):
// thread t: sub=t&3 (f32x4 chunk), rbase=t>>2 (64 row streams), 32 rows each,
// flat batches of 8. Shuffle+LDS reduce, store to ws[half*4096 + col].
// ONE grid.sync. Phase 2: R6 rowdot2 body, c[i] = partial0 + partial1.
__global__ __launch_bounds__(256) void fused_kernel(const float* __restrict__ x,
                                                    const float* __restrict__ W,
                                                    float* __restrict__ ws,
                                                    float* __restrict__ out) {
    const int t    = threadIdx.x;
    const int lane = t & 63;
    const int wave = t >> 6;

    // ---------- Phase 1 ----------
    __shared__ f32x4 red[4][4];
    for (int u = blockIdx.x; u < 512; u += gridDim.x) {
        const int ct   = u >> 1;           // 16-col tile
        const int half = u & 1;            // row half
        const int c0   = ct * 16;
        const int sub  = t & 3;
        const int rbase = (t >> 2) + half * 2048;

        f32x4 acc = {0.f, 0.f, 0.f, 0.f};
#pragma unroll
        for (int kb = 0; kb < 4; ++kb) {
            f32x4 v[8];
#pragma unroll
            for (int k = 0; k < 8; ++k)
                v[k] = ntload4(&W[(size_t)(rbase + 64 * (kb * 8 + k)) * N_COLS
                                  + c0 + sub * 4]);
#pragma unroll
            for (int k = 0; k < 8; ++k)
                acc += v[k];
        }
#pragma unroll
        for (int off = 32; off >= 4; off >>= 1) {
            acc.x += __shfl_down(acc.x, off, 64);
            acc.y += __shfl_down(acc.y, off, 64);
            acc.z += __shfl_down(acc.z, off, 64);
            acc.w += __shfl_down(acc.w, off, 64);
        }
        if (lane < 4) red[wave][lane] = acc;
        __syncthreads();
        if (t < 4) {
            const f32x4 s = red[0][t] + red[1][t] + red[2][t] + red[3][t];
            *reinterpret_cast<f32x4*>(&ws[half * N_COLS + c0 + t * 4]) = s;
        }
        __syncthreads();
    }

    cg::this_grid().sync();

    // ---------- Phase 2 ----------
    const int wid    = blockIdx.x * 4 + wave;
    const int nwaves = gridDim.x * 4;

    f32x4 c[16];
#pragma unroll
    for (int i = 0; i < 16; ++i) {
        const int idx = (i * 64 + lane) * 4;
        c[i] = *reinterpret_cast<const f32x4*>(&ws[idx])
             + *reinterpret_cast<const f32x4*>(&ws[N_COLS + idx]);
    }

    for (int row = wid; row < BATCH; row += nwaves) {
        const float* __restrict__ xr = x + (size_t)row * N_COLS;
        f32x4 v[16];
#pragma unroll
        for (int i = 0; i < 16; ++i)
            v[i] = ntload4(&xr[(i * 64 + lane) * 4]);

        float acc = 0.f;
#pragma unroll
        for (int i = 0; i < 16; ++i)
            acc += v[i].x * c[i].x + v[i].y * c[i].y +
                   v[i].z * c[i].z + v[i].w * c[i].w;

#pragma unroll
        for (int off = 32; off >= 1; off >>= 1)
            acc += __shfl_down(acc, off, 64);

        if (lane == 0) out[row] = acc * SCALE;
    }
}

// ================= Fallback (R6 exact, non-cooperative) =================
__global__ __launch_bounds__(256) void colsum_ex_kernel(const float* __restrict__ W,
                                                        float* __restrict__ ws) {
    const int t     = threadIdx.x;
    const int c0    = blockIdx.x * 16;
    const int sub   = t & 3;
    const int rbase = t >> 2;
    const int lane  = t & 63;
    const int wave  = t >> 6;

    f32x4 acc = {0.f, 0.f, 0.f, 0.f};
#pragma unroll 8
    for (int k = 0; k < 64; ++k)
        acc += ntload4(&W[(size_t)(rbase + 64 * k) * N_COLS + c0 + sub * 4]);
#pragma unroll
    for (int off = 32; off >= 4; off >>= 1) {
        acc.x += __shfl_down(acc.x, off, 64);
        acc.y += __shfl_down(acc.y, off, 64);
        acc.z += __shfl_down(acc.z, off, 64);
        acc.w += __shfl_down(acc.w, off, 64);
    }
    __shared__ f32x4 red[4][4];
    if (lane < 4) red[wave][lane] = acc;
    __syncthreads();
    if (t < 4) {
        const f32x4 s = red[0][t] + red[1][t] + red[2][t] + red[3][t];
        *reinterpret_cast<f32x4*>(&ws[c0 + t * 4]) = s;
    }
}

__global__ __launch_bounds__(256) void rowdot2_kernel(const float* __restrict__ x,
                                                      const float* __restrict__ ws,
                                                      float* __restrict__ out) {
    const int lane = threadIdx.x & 63;
    const int wid  = blockIdx.x * 4 + (threadIdx.x >> 6);

    f32x4 c[16];
#pragma unroll
    for (int i = 0; i < 16; ++i)
        c[i] = *reinterpret_cast<const f32x4*>(&ws[(i * 64 + lane) * 4]);

#pragma unroll
    for (int rep = 0; rep < 2; ++rep) {
        const int row = wid + rep * 8192;
        const float* __restrict__ xr = x + (size_t)row * N_COLS;
        f32x4 v[16];
#pragma unroll
        for (int i = 0; i < 16; ++i)
            v[i] = ntload4(&xr[(i * 64 + lane) * 4]);
        float acc = 0.f;
#pragma unroll
        for (int i = 0; i < 16; ++i)
            acc += v[i].x * c[i].x + v[i].y * c[i].y +
                   v[i].z * c[i].z + v[i].w * c[i].w;
#pragma unroll
        for (int off = 32; off >= 1; off >>= 1)
            acc += __shfl_down(acc, off, 64);
        if (lane == 0) out[row] = acc * SCALE;
    }
}

extern "C" void kernel_launch(void* const* d_in, const int* in_sizes, int n_in,
                              void* d_out, int out_size, void* d_ws, size_t ws_size,
                              hipStream_t stream) {
    const float* x = (const float*)d_in[0];   // (16384, 4096)
    const float* W = (const float*)d_in[1];   // (4096, 4096)
    float* out = (float*)d_out;               // (16384, 1)
    float* ws  = (float*)d_ws;                // >= 32 KB scratch (2 x 4096 f32)

    int bpc = 0;
    (void)hipOccupancyMaxActiveBlocksPerMultiprocessor(&bpc, fused_kernel, 256, 0);
    int grid = bpc * 256;                     // 256 CUs on MI355X
    if (grid > 512) grid = 512;               // 512 phase-1 units

    hipError_t err = hipErrorUnknown;
    if (grid >= 256) {
        void* args[] = {(void*)&x, (void*)&W, (void*)&ws, (void*)&out};
        err = hipLaunchCooperativeKernel((const void*)fused_kernel, dim3(grid),
                                         dim3(256), args, 0, stream);
    }
    if (err != hipSuccess) {
        // Fallback: R6 two-launch path.
        colsum_ex_kernel<<<256, 256, 0, stream>>>(W, ws);
        rowdot2_kernel<<<2048, 256, 0, stream>>>(x, ws, out);
    }
}

// Round 9
// 93.112 us; speedup vs baseline: 1.1618x; 1.1618x over previous
//
#include <hip/hip_runtime.h>

// x (16384 x 4096 fp32), W (4096 x 4096 fp32)
// out[b] = 0.75 * dot(x[b,:], colsum(W)), shape (16384,1) fp32.
// MEASUREMENT ROUND: colsum launched 2x, rowdot row-loop repeated 4x inside
// the kernel (both idempotent). Goal: rowdot becomes the longest dispatch so
// rocprof top-5 finally shows ITS counters; colsum cost falls out of the dur
// delta vs R6's 68.7 us.

#define N_COLS 4096
#define BATCH  16384
#define SCALE  0.75f   // SCALING_FACTOR / 2.0

typedef float f32x4 __attribute__((ext_vector_type(4)));

__device__ __forceinline__ f32x4 ntload4(const float* p) {
    return __builtin_nontemporal_load(reinterpret_cast<const f32x4*>(p));
}

// ---------------- Kernel 1: column-sum of W (EXACT R6 version) ----------------
__global__ __launch_bounds__(256) void colsum_ex_kernel(const float* __restrict__ W,
                                                        float* __restrict__ ws) {
    const int t     = threadIdx.x;
    const int c0    = blockIdx.x * 16;
    const int sub   = t & 3;
    const int rbase = t >> 2;
    const int lane  = t & 63;
    const int wave  = t >> 6;

    f32x4 acc = {0.f, 0.f, 0.f, 0.f};
#pragma unroll 8
    for (int k = 0; k < 64; ++k)
        acc += ntload4(&W[(size_t)(rbase + 64 * k) * N_COLS + c0 + sub * 4]);
#pragma unroll
    for (int off = 32; off >= 4; off >>= 1) {
        acc.x += __shfl_down(acc.x, off, 64);
        acc.y += __shfl_down(acc.y, off, 64);
        acc.z += __shfl_down(acc.z, off, 64);
        acc.w += __shfl_down(acc.w, off, 64);
    }
    __shared__ f32x4 red[4][4];
    if (lane < 4) red[wave][lane] = acc;
    __syncthreads();
    if (t < 4) {
        const f32x4 s = red[0][t] + red[1][t] + red[2][t] + red[3][t];
        *reinterpret_cast<f32x4*>(&ws[c0 + t * 4]) = s;
    }
}

// ---------------- Kernel 2: R6 rowdot2 body, row work repeated 4x ----------------
__global__ __launch_bounds__(256) void rowdot4_kernel(const float* __restrict__ x,
                                                      const float* __restrict__ ws,
                                                      float* __restrict__ out) {
    const int lane = threadIdx.x & 63;
    const int wid  = blockIdx.x * 4 + (threadIdx.x >> 6);   // 0..8191

    f32x4 c[16];
#pragma unroll
    for (int i = 0; i < 16; ++i)
        c[i] = *reinterpret_cast<const f32x4*>(&ws[(i * 64 + lane) * 4]);

    for (int iter = 0; iter < 4; ++iter) {   // measurement repeat (idempotent)
#pragma unroll
        for (int rep = 0; rep < 2; ++rep) {
            const int row = wid + rep * 8192;
            const float* __restrict__ xr = x + (size_t)row * N_COLS;

            f32x4 v[16];
#pragma unroll
            for (int i = 0; i < 16; ++i)
                v[i] = ntload4(&xr[(i * 64 + lane) * 4]);

            float acc = 0.f;
#pragma unroll
            for (int i = 0; i < 16; ++i)
                acc += v[i].x * c[i].x + v[i].y * c[i].y +
                       v[i].z * c[i].z + v[i].w * c[i].w;

#pragma unroll
            for (int off = 32; off >= 1; off >>= 1)
                acc += __shfl_down(acc, off, 64);

            if (lane == 0) out[row] = acc * SCALE;
        }
    }
}

extern "C" void kernel_launch(void* const* d_in, const int* in_sizes, int n_in,
                              void* d_out, int out_size, void* d_ws, size_t ws_size,
                              hipStream_t stream) {
    const float* x = (const float*)d_in[0];   // (16384, 4096)
    const float* W = (const float*)d_in[1];   // (4096, 4096)
    float* out = (float*)d_out;               // (16384, 1)
    float* ws  = (float*)d_ws;

    colsum_ex_kernel<<<256, 256, 0, stream>>>(W, ws);   // measured twice:
    colsum_ex_kernel<<<256, 256, 0, stream>>>(W, ws);   // delta = colsum + gap
    rowdot4_kernel<<<2048, 256, 0, stream>>>(x, ws, out);
}

// Round 10
// 61.260 us; speedup vs baseline: 1.7658x; 1.5200x over previous
//
#include <hip/hip_runtime.h>

// x (16384 x 4096 fp32), W (4096 x 4096 fp32)
// out[b] = 0.75 * dot(x[b,:], colsum(W)), shape (16384,1) fp32.
// Decomposition from R9 measurement: colsum ~23 us (starved), rowdot ~43 us
// (near BW ceiling). This round: high-occupancy atomic-free colsum partials
// (8 waves/CU, 16-deep flat batches, contiguous 1KB wave-loads) + tiny L2
// reduce. rowdot unchanged (R6 exact).

#define N_COLS 4096
#define BATCH  16384
#define SCALE  0.75f   // SCALING_FACTOR / 2.0
#define NSLOT  64      // partial slots (one per (col-tile-row-chunk) block)

typedef float f32x4 __attribute__((ext_vector_type(4)));

__device__ __forceinline__ f32x4 ntload4(const float* p) {
    return __builtin_nontemporal_load(reinterpret_cast<const f32x4*>(p));
}

// ---------- Kernel 1a: colsum partials (atomic-free, memset-free) ----------
// grid (4 col-tiles, 64 row-chunks) = 256 blocks x 512 threads = 8 waves/CU.
// Thread group gh=t>>8 (2 groups of 256) splits the 64-row chunk; thread owns
// 4 consecutive cols (f32x4, 1KB contiguous per wave-instr); 32 rows as two
// flat batches of 16 independent loads (16 KB/wave in flight). Groups combine
// via LDS; block writes its exclusive partial slot. No atomics, no memset.
__global__ __launch_bounds__(512) void colsum_part_kernel(const float* __restrict__ W,
                                                          float* __restrict__ part) {
    const int t  = threadIdx.x;
    const int tg = t & 255;          // col group within block
    const int gh = t >> 8;           // row half (0/1)
    const int colBase = blockIdx.x * 1024 + tg * 4;
    const int row0    = blockIdx.y * 64 + gh * 32;

    f32x4 acc = {0.f, 0.f, 0.f, 0.f};
#pragma unroll
    for (int half = 0; half < 2; ++half) {
        f32x4 v[16];
#pragma unroll
        for (int r = 0; r < 16; ++r)
            v[r] = ntload4(&W[(size_t)(row0 + half * 16 + r) * N_COLS + colBase]);
#pragma unroll
        for (int r = 0; r < 16; ++r)
            acc += v[r];
    }

    __shared__ f32x4 lds[256];
    if (gh == 1) lds[tg] = acc;
    __syncthreads();
    if (gh == 0) {
        acc += lds[tg];
        *reinterpret_cast<f32x4*>(&part[(size_t)blockIdx.y * N_COLS + colBase]) = acc;
    }
}

// ---------- Kernel 1b: reduce 64 partial slots -> ws[0..4095] ----------
// 1 MB of partials is L2-resident. grid 16 x 64 threads; thread owns one
// f32x4 column group, sums 64 slots.
__global__ __launch_bounds__(64) void colsum_reduce_kernel(const float* __restrict__ part,
                                                           float* __restrict__ ws) {
    const int c4 = blockIdx.x * 64 + threadIdx.x;   // 0..1023
    f32x4 s = {0.f, 0.f, 0.f, 0.f};
#pragma unroll 8
    for (int k = 0; k < NSLOT; ++k)
        s += *reinterpret_cast<const f32x4*>(&part[(size_t)k * N_COLS + c4 * 4]);
    *reinterpret_cast<f32x4*>(&ws[c4 * 4]) = s;
}

// ---------- Fallback colsum (if ws too small): memset + atomics ----------
__global__ __launch_bounds__(256) void colsum_atomic_kernel(const float* __restrict__ W,
                                                            float* __restrict__ ws) {
    const int colBase = blockIdx.x * 1024 + threadIdx.x * 4;
    const int row0    = blockIdx.y * 32;
    f32x4 acc = {0.f, 0.f, 0.f, 0.f};
#pragma unroll
    for (int kb = 0; kb < 2; ++kb) {
        f32x4 v[16];
#pragma unroll
        for (int r = 0; r < 16; ++r)
            v[r] = ntload4(&W[(size_t)(row0 + kb * 16 + r) * N_COLS + colBase]);
#pragma unroll
        for (int r = 0; r < 16; ++r)
            acc += v[r];
    }
    atomicAdd(&ws[colBase + 0], acc.x);
    atomicAdd(&ws[colBase + 1], acc.y);
    atomicAdd(&ws[colBase + 2], acc.z);
    atomicAdd(&ws[colBase + 3], acc.w);
}

// ---------------- Kernel 2: out[b] = SCALE * dot(x[b,:], ws) ----------------
// EXACT R6 version (near BW ceiling per R9 decomposition).
__global__ __launch_bounds__(256) void rowdot2_kernel(const float* __restrict__ x,
                                                      const float* __restrict__ ws,
                                                      float* __restrict__ out) {
    const int lane = threadIdx.x & 63;
    const int wid  = blockIdx.x * 4 + (threadIdx.x >> 6);   // 0..8191

    f32x4 c[16];
#pragma unroll
    for (int i = 0; i < 16; ++i)
        c[i] = *reinterpret_cast<const f32x4*>(&ws[(i * 64 + lane) * 4]);

#pragma unroll
    for (int rep = 0; rep < 2; ++rep) {
        const int row = wid + rep * 8192;
        const float* __restrict__ xr = x + (size_t)row * N_COLS;

        f32x4 v[16];
#pragma unroll
        for (int i = 0; i < 16; ++i)
            v[i] = ntload4(&xr[(i * 64 + lane) * 4]);

        float acc = 0.f;
#pragma unroll
        for (int i = 0; i < 16; ++i)
            acc += v[i].x * c[i].x + v[i].y * c[i].y +
                   v[i].z * c[i].z + v[i].w * c[i].w;

#pragma unroll
        for (int off = 32; off >= 1; off >>= 1)
            acc += __shfl_down(acc, off, 64);

        if (lane == 0) out[row] = acc * SCALE;
    }
}

extern "C" void kernel_launch(void* const* d_in, const int* in_sizes, int n_in,
                              void* d_out, int out_size, void* d_ws, size_t ws_size,
                              hipStream_t stream) {
    const float* x = (const float*)d_in[0];   // (16384, 4096)
    const float* W = (const float*)d_in[1];   // (4096, 4096)
    float* out = (float*)d_out;               // (16384, 1)
    float* ws  = (float*)d_ws;                // final colsum at [0, 4096)

    const size_t need = (size_t)(NSLOT + 1) * N_COLS * sizeof(float);
    if (ws_size >= need) {
        float* part = ws + N_COLS;            // 64 slots x 16 KB = 1 MB
        colsum_part_kernel<<<dim3(4, NSLOT), 512, 0, stream>>>(W, part);
        colsum_reduce_kernel<<<16, 64, 0, stream>>>(part, ws);
    } else {
        (void)hipMemsetAsync(ws, 0, N_COLS * sizeof(float), stream);
        colsum_atomic_kernel<<<dim3(4, 128), 256, 0, stream>>>(W, ws);
    }
    rowdot2_kernel<<<2048, 256, 0, stream>>>(x, ws, out);
}